// Round 3
// baseline (3093.372 us; speedup 1.0000x reference)
//
#include <hip/hip_runtime.h>

// Qwen2 FP8 MLP: x[4096,3584] -> silu(x@Wg^T*sg)*(x@Wu^T*su) -> @Wd^T*sd
// Strategy: cast fp8-valued fp32 weights to bf16 LOSSLESSLY (no scale fold),
// bf16 MFMA GEMMs (m97 structure), scales applied in fp32 epilogues.

constexpr int T_ = 4096;    // tokens
constexpr int H_ = 3584;    // hidden
constexpr int I_ = 18944;   // intermediate

typedef short s8v __attribute__((ext_vector_type(8)));   // 8 x bf16 bits (4 VGPR)
typedef float f4v __attribute__((ext_vector_type(4)));   // MFMA accumulator

#define GLOAD_LDS16(g, l) __builtin_amdgcn_global_load_lds( \
    (const __attribute__((address_space(1))) void*)(g),     \
    (__attribute__((address_space(3))) void*)(l), 16, 0, 0)

__device__ __forceinline__ unsigned short f2bf(float f) {
  unsigned int b = __float_as_uint(f);
  return (unsigned short)((b + 0x7FFFu + ((b >> 16) & 1)) >> 16);
}

// ---------------- prepass: fp32 -> bf16 cast (vectorized) ----------------
__global__ void cast_f32_bf16_k(const float* __restrict__ in,
                                unsigned short* __restrict__ out, int n4) {
  int stride = gridDim.x * blockDim.x;
  for (int i = blockIdx.x * blockDim.x + threadIdx.x; i < n4; i += stride) {
    float4 v = reinterpret_cast<const float4*>(in)[i];
    ushort4 o;
    o.x = f2bf(v.x); o.y = f2bf(v.y); o.z = f2bf(v.z); o.w = f2bf(v.w);
    reinterpret_cast<ushort4*>(out)[i] = o;
  }
}

// ---------------- GEMM1: fused gate/up + SiLU*mul ----------------
// grid: x = T_/128 (M tiles), y = I_/64 (col tiles)
// block 256 thr = 4 waves (2x2); wave tile 64 rows x 32 cols, gate+up acc.
__global__ __launch_bounds__(256, 2) void gemm1_fused(
    const unsigned short* __restrict__ Xb,   // [T_,H_] bf16
    const unsigned short* __restrict__ Wb,   // [2I_,H_] bf16 (unscaled fp8 values)
    const float* __restrict__ sgu,           // [2I_] row scales
    unsigned short* __restrict__ Hb)         // [T_,I_] bf16 out
{
  __shared__ unsigned short lA[128 * 32];
  __shared__ unsigned short lG[64 * 32];
  __shared__ unsigned short lU[64 * 32];

  const int tid = threadIdx.x;
  const int wave = tid >> 6, lane = tid & 63;
  const int wr = wave >> 1, wc = wave & 1;
  const int m0 = blockIdx.x * 128;
  const int n0 = blockIdx.y * 64;

  f4v accg[4][2], accu[4][2];
#pragma unroll
  for (int i = 0; i < 4; ++i)
#pragma unroll
    for (int j = 0; j < 2; ++j)
#pragma unroll
      for (int r = 0; r < 4; ++r) { accg[i][j][r] = 0.f; accu[i][j][r] = 0.f; }

  const int lrow = lane & 15;
  const int kofs = (lane >> 4) * 8;

  for (int k0 = 0; k0 < H_; k0 += 32) {
    // ---- stage tiles via global_load_lds (16B/lane, wave-uniform LDS base) ----
    const int wb = wave * 1024;          // wave's byte base within a 4096B round
    const int lb = wb + lane * 16;       // this lane's byte offset
#pragma unroll
    for (int r = 0; r < 2; ++r) {        // A: 128 rows x 64B = 8192B = 2 rounds
      int off = r * 4096 + lb;
      int row = off >> 6, colb = off & 63;
      GLOAD_LDS16((const char*)(Xb + (size_t)(m0 + row) * H_ + k0) + colb,
                  (char*)lA + r * 4096 + wb);
    }
    {                                    // G and U: 64 rows x 64B = 4096B each
      int row = lb >> 6, colb = lb & 63;
      GLOAD_LDS16((const char*)(Wb + (size_t)(n0 + row) * H_ + k0) + colb,
                  (char*)lG + wb);
      GLOAD_LDS16((const char*)(Wb + (size_t)(I_ + n0 + row) * H_ + k0) + colb,
                  (char*)lU + wb);
    }
    __syncthreads();   // compiler emits vmcnt(0) drain before barrier

    // ---- compute: 16 MFMA / wave / K-step ----
    s8v a[4], g[2], u[2];
#pragma unroll
    for (int mi = 0; mi < 4; ++mi)
      a[mi] = *(const s8v*)&lA[(wr * 64 + mi * 16 + lrow) * 32 + kofs];
#pragma unroll
    for (int ni = 0; ni < 2; ++ni) {
      g[ni] = *(const s8v*)&lG[(wc * 32 + ni * 16 + lrow) * 32 + kofs];
      u[ni] = *(const s8v*)&lU[(wc * 32 + ni * 16 + lrow) * 32 + kofs];
    }
#pragma unroll
    for (int mi = 0; mi < 4; ++mi)
#pragma unroll
      for (int ni = 0; ni < 2; ++ni) {
        accg[mi][ni] = __builtin_amdgcn_mfma_f32_16x16x32_bf16(a[mi], g[ni], accg[mi][ni], 0, 0, 0);
        accu[mi][ni] = __builtin_amdgcn_mfma_f32_16x16x32_bf16(a[mi], u[ni], accu[mi][ni], 0, 0, 0);
      }
    __syncthreads();
  }

  // ---- epilogue: scale, SiLU*mul, bf16 store ----
#pragma unroll
  for (int ni = 0; ni < 2; ++ni) {
    int col = n0 + wc * 32 + ni * 16 + lrow;
    float sg = sgu[col];
    float su = sgu[col + I_];
#pragma unroll
    for (int mi = 0; mi < 4; ++mi) {
      int rbase = m0 + wr * 64 + mi * 16 + (lane >> 4) * 4;
#pragma unroll
      for (int r = 0; r < 4; ++r) {
        float gv = accg[mi][ni][r] * sg;
        float uv = accu[mi][ni][r] * su;
        float hv = gv / (1.f + __expf(-gv)) * uv;
        Hb[(size_t)(rbase + r) * I_ + col] = f2bf(hv);
      }
    }
  }
}

// ---------------- GEMM2: out = h @ Wd^T * sd ----------------
// grid: x = T_/128 (M tiles), y = H_/128 (N tiles); 128x128 tile, wave 64x64.
__global__ __launch_bounds__(256, 2) void gemm2_k(
    const unsigned short* __restrict__ Hb,   // [T_,I_] bf16
    const unsigned short* __restrict__ Wd,   // [H_,I_] bf16 (unscaled)
    const float* __restrict__ sd,            // [H_]
    float* __restrict__ Out)                 // [T_,H_] fp32
{
  __shared__ unsigned short lA[128 * 32];
  __shared__ unsigned short lB[128 * 32];

  const int tid = threadIdx.x;
  const int wave = tid >> 6, lane = tid & 63;
  const int wr = wave >> 1, wc = wave & 1;
  const int m0 = blockIdx.x * 128;
  const int n0 = blockIdx.y * 128;

  f4v acc[4][4];
#pragma unroll
  for (int i = 0; i < 4; ++i)
#pragma unroll
    for (int j = 0; j < 4; ++j)
#pragma unroll
      for (int r = 0; r < 4; ++r) acc[i][j][r] = 0.f;

  const int lrow = lane & 15;
  const int kofs = (lane >> 4) * 8;

  for (int k0 = 0; k0 < I_; k0 += 32) {
    const int wb = wave * 1024;
    const int lb = wb + lane * 16;
#pragma unroll
    for (int r = 0; r < 2; ++r) {
      int off = r * 4096 + lb;
      int row = off >> 6, colb = off & 63;
      GLOAD_LDS16((const char*)(Hb + (size_t)(m0 + row) * I_ + k0) + colb,
                  (char*)lA + r * 4096 + wb);
      GLOAD_LDS16((const char*)(Wd + (size_t)(n0 + row) * I_ + k0) + colb,
                  (char*)lB + r * 4096 + wb);
    }
    __syncthreads();

    s8v a[4], b[4];
#pragma unroll
    for (int mi = 0; mi < 4; ++mi)
      a[mi] = *(const s8v*)&lA[(wr * 64 + mi * 16 + lrow) * 32 + kofs];
#pragma unroll
    for (int ni = 0; ni < 4; ++ni)
      b[ni] = *(const s8v*)&lB[(wc * 64 + ni * 16 + lrow) * 32 + kofs];
#pragma unroll
    for (int mi = 0; mi < 4; ++mi)
#pragma unroll
      for (int ni = 0; ni < 4; ++ni)
        acc[mi][ni] = __builtin_amdgcn_mfma_f32_16x16x32_bf16(a[mi], b[ni], acc[mi][ni], 0, 0, 0);
    __syncthreads();
  }

#pragma unroll
  for (int ni = 0; ni < 4; ++ni) {
    int col = n0 + wc * 64 + ni * 16 + lrow;
    float s = sd[col];
#pragma unroll
    for (int mi = 0; mi < 4; ++mi) {
      int rbase = m0 + wr * 64 + mi * 16 + (lane >> 4) * 4;
#pragma unroll
      for (int r = 0; r < 4; ++r)
        Out[(size_t)(rbase + r) * H_ + col] = acc[mi][ni][r] * s;
    }
  }
}

extern "C" void kernel_launch(void* const* d_in, const int* in_sizes, int n_in,
                              void* d_out, int out_size, void* d_ws, size_t ws_size,
                              hipStream_t stream) {
  const float* x   = (const float*)d_in[0];   // [4096,3584]
  const float* wgu = (const float*)d_in[1];   // [37888,3584] fp8-valued fp32
  const float* sgu = (const float*)d_in[2];   // [37888,1]
  const float* wd  = (const float*)d_in[3];   // [3584,18944]
  const float* sd  = (const float*)d_in[4];   // [3584,1]
  float* out = (float*)d_out;                 // [4096,3584] fp32

  // ws layout (bf16 buffers): xb | wgu_b | wd_b | h   (~592 MB total)
  unsigned short* xb   = (unsigned short*)d_ws;
  unsigned short* wgub = xb + (size_t)T_ * H_;
  unsigned short* wdb  = wgub + (size_t)2 * I_ * H_;
  unsigned short* hb   = wdb + (size_t)H_ * I_;

  cast_f32_bf16_k<<<2048, 256, 0, stream>>>(x, xb, T_ * H_ / 4);
  cast_f32_bf16_k<<<2048, 256, 0, stream>>>(wgu, wgub, 2 * I_ * H_ / 4);
  cast_f32_bf16_k<<<2048, 256, 0, stream>>>(wd, wdb, H_ * I_ / 4);

  dim3 g1(T_ / 128, I_ / 64);     // 32 x 296
  gemm1_fused<<<g1, 256, 0, stream>>>(xb, wgub, sgu, hb);

  dim3 g2(T_ / 128, H_ / 128);    // 32 x 28
  gemm2_k<<<g2, 256, 0, stream>>>(hb, wdb, sd, out);
}

// Round 7
// 2546.407 us; speedup vs baseline: 1.2148x; 1.2148x over previous
//
#include <hip/hip_runtime.h>

// Qwen2 FP8 MLP on MI355X — 256x256 8-phase MFMA GEMMs (T1+T2+T3+T4+T5).
// fp8-valued fp32 weights cast LOSSLESSLY to bf16; scales in fp32 epilogues.
// gemm1 fuses gate/up + SiLU*mul in-wave via interleaved B-row mapping.
// R6 fix: do_stage clamps (jj>=NT4 -> 0) instead of skipping, keeping the
// vmcnt(2) ledger uniform at the K-boundary (skip left last tile's B-h1
// un-drained -> stale read -> absmax 1.33).

constexpr int T_ = 4096;    // tokens
constexpr int H_ = 3584;    // hidden
constexpr int I_ = 18944;   // intermediate

typedef short s8v __attribute__((ext_vector_type(8)));   // 8 bf16 (4 VGPR)
typedef float f4v __attribute__((ext_vector_type(4)));   // MFMA acc

#define GLOAD_LDS16(g, l) __builtin_amdgcn_global_load_lds( \
    (const __attribute__((address_space(1))) void*)(g),     \
    (__attribute__((address_space(3))) void*)(l), 16, 0, 0)

__device__ __forceinline__ unsigned short f2bf(float f) {
  unsigned int b = __float_as_uint(f);
  return (unsigned short)((b + 0x7FFFu + ((b >> 16) & 1)) >> 16);
}

// ---------------- prepass: fp32 -> bf16 cast ----------------
__global__ void cast_f32_bf16_k(const float* __restrict__ in,
                                unsigned short* __restrict__ out, int n4) {
  int stride = gridDim.x * blockDim.x;
  for (int i = blockIdx.x * blockDim.x + threadIdx.x; i < n4; i += stride) {
    float4 v = reinterpret_cast<const float4*>(in)[i];
    ushort4 o;
    o.x = f2bf(v.x); o.y = f2bf(v.y); o.z = f2bf(v.z); o.w = f2bf(v.w);
    reinterpret_cast<ushort4*>(out)[i] = o;
  }
}

// ---------------- 256x256 8-phase GEMM ----------------
// MODE 0: gemm1. B rows interleave gate/up in 32-row groups; epilogue does
//         silu(g*sg)*(u*su) -> bf16 Hb[T_,I_]. n0 covers 128 h-cols.
// MODE 1: gemm2. Plain B^T; epilogue scales by sd[col] -> fp32 Out[T_,H_].
// Geometry: BM=BN=256, BK=64, 8 waves (2Mx4N), wave tile 128x64,
// frags 8mi x 4ni x 2kk of 16x16x32 bf16. LDS 128KB (2 dbuf x (A,B) x 32KB).
// Swizzle st_16x32: elem col ^= 16 when (row&4) — linear LDS dest,
// inverse-swizzled GLOBAL source (rule 21), swizzled ds_read.
template <int KDIM, int CPX, int MODE>
__global__ __launch_bounds__(512, 2) void gemm8p(
    const unsigned short* __restrict__ A,   // [T_,KDIM] bf16
    const unsigned short* __restrict__ B,   // weights bf16 [*,KDIM]
    const float* __restrict__ S,            // per-out-channel scales
    void* __restrict__ Cout)
{
  constexpr int NT = KDIM / 64;             // K-tiles (56 / 296 — both even)
  constexpr int NT4 = 4 * NT;               // half-tile stages total
  __shared__ unsigned short lds[2][2][2][8192]; // [buf][A/B][half][128*64]

  const int tid = threadIdx.x;
  const int wave = tid >> 6, lane = tid & 63;
  const int wm = wave >> 2, wn = wave & 3;
  const int lrow = lane & 15, ksel = lane >> 4;
  const int sw = (lrow & 4) << 2;           // read-side XOR (elements)
  const int wvb = (wave << 10);             // wave's 1KB slice (bytes)

  const int bid = blockIdx.x;
  const int sid = (bid & 7) * CPX + (bid >> 3);   // XCD-bijective swizzle
  const int m0 = (sid & 15) * 256;
  const int n0 = (sid >> 4) * (MODE == 0 ? 128 : 256);

  f4v acc[8][4];
#pragma unroll
  for (int i = 0; i < 8; ++i)
#pragma unroll
    for (int jv = 0; jv < 4; ++jv)
#pragma unroll
      for (int r = 0; r < 4; ++r) acc[i][jv][r] = 0.f;

  s8v af[4][2], bfr[4][2];

  // stage one half-tile: j -> (ktile, quarter). q: 0=A-h0 1=A-h1 2=B-h0 3=B-h1
  // jj>=NT4: CLAMP to 0 (harmless re-stage of ktile0 A-h0 into dead buf0) so
  // every do_stage issues exactly 2 loads -> vmcnt(2) ledger stays uniform.
  auto do_stage = [&](int jj) {
    if (jj >= NT4) jj = 0;
    const int kt = jj >> 2, q = jj & 3;
    const int buf = kt & 1, k0 = kt << 6;
    const int isB = q >> 1, h = q & 1;
#pragma unroll
    for (int r = 0; r < 2; ++r) {
      int o = r * 8192 + tid * 16;          // byte offset within half (linear)
      int row = o >> 7;
      int cb = (o & 127) ^ ((row & 4) << 3);  // inverse-swizzled source col
      int grow;
      const unsigned short* G;
      if (!isB) { G = A; grow = m0 + h * 128 + row; }
      else {
        G = B;
        if (MODE == 0) {                    // gate/up interleave, 32-row groups
          int rg = h * 128 + row;
          int p = ((rg >> 6) << 5) | (rg & 31);
          grow = n0 + p + (((rg >> 5) & 1) ? I_ : 0);
        } else {
          grow = n0 + h * 128 + row;
        }
      }
      GLOAD_LDS16((const char*)(G + (size_t)grow * KDIM + k0) + cb,
                  (char*)&lds[buf][isB][h][0] + r * 8192 + wvb);
    }
  };

#define LOADA(BUF, MH)                                                        \
  _Pragma("unroll") for (int m = 0; m < 4; ++m)                               \
  _Pragma("unroll") for (int kk = 0; kk < 2; ++kk)                            \
    af[m][kk] = *(const s8v*)&lds[BUF][0][wm]                                 \
        [((MH) * 64 + m * 16 + lrow) * 64 + ((kk * 32 + ksel * 8) ^ sw)];

#define LOADB(BUF, NH)                                                        \
  _Pragma("unroll") for (int n = 0; n < 2; ++n)                               \
  _Pragma("unroll") for (int kk = 0; kk < 2; ++kk)                            \
    bfr[(NH) * 2 + n][kk] = *(const s8v*)&lds[BUF][1][wn >> 1]                \
        [((wn & 1) * 64 + (NH) * 32 + n * 16 + lrow) * 64 +                   \
         ((kk * 32 + ksel * 8) ^ sw)];

#define MFMAQ(MH, NH)                                                         \
  _Pragma("unroll") for (int m = 0; m < 4; ++m)                               \
  _Pragma("unroll") for (int n = 0; n < 2; ++n)                               \
  _Pragma("unroll") for (int kk = 0; kk < 2; ++kk)                            \
    acc[(MH) * 4 + m][(NH) * 2 + n] = __builtin_amdgcn_mfma_f32_16x16x32_bf16(\
        af[m][kk], bfr[(NH) * 2 + n][kk], acc[(MH) * 4 + m][(NH) * 2 + n],    \
        0, 0, 0);

  // ---- prologue: ktile0 (4 halves) + ktile1 A0; drain ktile0 ----
  for (int jj = 0; jj < 5; ++jj) do_stage(jj);
  asm volatile("s_waitcnt vmcnt(2)" ::: "memory");
  __builtin_amdgcn_s_barrier();

  int j = 5;
  for (int kt = 0; kt < NT; ++kt) {
    const int buf = kt & 1;
    // phase 0: quadrant (mh0, nh0)
    LOADA(buf, 0); LOADB(buf, 0);
    do_stage(j++);
    __builtin_amdgcn_s_barrier();
    asm volatile("s_waitcnt lgkmcnt(0)" ::: "memory");
    __builtin_amdgcn_s_setprio(1); MFMAQ(0, 0); __builtin_amdgcn_s_setprio(0);
    __builtin_amdgcn_s_barrier();
    // phase 1: (mh0, nh1)
    LOADB(buf, 1);
    do_stage(j++);
    __builtin_amdgcn_s_barrier();
    asm volatile("s_waitcnt lgkmcnt(0)" ::: "memory");
    __builtin_amdgcn_s_setprio(1); MFMAQ(0, 1); __builtin_amdgcn_s_setprio(0);
    __builtin_amdgcn_s_barrier();
    // phase 2: (mh1, nh1)
    LOADA(buf, 1);
    do_stage(j++);
    __builtin_amdgcn_s_barrier();
    asm volatile("s_waitcnt lgkmcnt(0)" ::: "memory");
    __builtin_amdgcn_s_setprio(1); MFMAQ(1, 1); __builtin_amdgcn_s_setprio(0);
    __builtin_amdgcn_s_barrier();
    // phase 3: (mh1, nh0) — register-resident; counted vmcnt checkpoint
    do_stage(j++);
    __builtin_amdgcn_s_barrier();
    __builtin_amdgcn_s_setprio(1); MFMAQ(1, 0); __builtin_amdgcn_s_setprio(0);
    asm volatile("s_waitcnt vmcnt(2)" ::: "memory");
    __builtin_amdgcn_s_barrier();
  }

  // ---- epilogue ----
  if (MODE == 0) {
    unsigned short* Hb = (unsigned short*)Cout;
#pragma unroll
    for (int np = 0; np < 2; ++np) {
      int colh = n0 + wn * 32 + np * 16 + lrow;
      float sg = S[colh], su = S[I_ + colh];
#pragma unroll
      for (int mi = 0; mi < 8; ++mi) {
        int r0 = m0 + wm * 128 + mi * 16 + ksel * 4;
#pragma unroll
        for (int rg = 0; rg < 4; ++rg) {
          float g = acc[mi][np][rg] * sg;
          float u = acc[mi][np + 2][rg] * su;
          float h = g / (1.f + __expf(-g)) * u;
          Hb[(size_t)(r0 + rg) * I_ + colh] = f2bf(h);
        }
      }
    }
  } else {
    float* O = (float*)Cout;
#pragma unroll
    for (int ni = 0; ni < 4; ++ni) {
      int col = n0 + wn * 64 + ni * 16 + lrow;
      float s = S[col];
#pragma unroll
      for (int mi = 0; mi < 8; ++mi) {
        int r0 = m0 + wm * 128 + mi * 16 + ksel * 4;
#pragma unroll
        for (int rg = 0; rg < 4; ++rg)
          O[(size_t)(r0 + rg) * H_ + col] = acc[mi][ni][rg] * s;
      }
    }
  }
#undef LOADA
#undef LOADB
#undef MFMAQ
}

extern "C" void kernel_launch(void* const* d_in, const int* in_sizes, int n_in,
                              void* d_out, int out_size, void* d_ws, size_t ws_size,
                              hipStream_t stream) {
  const float* x   = (const float*)d_in[0];   // [4096,3584]
  const float* wgu = (const float*)d_in[1];   // [37888,3584]
  const float* sgu = (const float*)d_in[2];   // [37888]
  const float* wd  = (const float*)d_in[3];   // [3584,18944]
  const float* sd  = (const float*)d_in[4];   // [3584]
  float* out = (float*)d_out;                 // [4096,3584] fp32

  // ws: xb | wgu_b | wd_b | hb  (~592 MB, same as validated baseline)
  unsigned short* xb   = (unsigned short*)d_ws;
  unsigned short* wgub = xb + (size_t)T_ * H_;
  unsigned short* wdb  = wgub + (size_t)2 * I_ * H_;
  unsigned short* hb   = wdb + (size_t)H_ * I_;

  cast_f32_bf16_k<<<2048, 256, 0, stream>>>(x, xb, T_ * H_ / 4);
  cast_f32_bf16_k<<<2048, 256, 0, stream>>>(wgu, wgub, 2 * I_ * H_ / 4);
  cast_f32_bf16_k<<<2048, 256, 0, stream>>>(wd, wdb, H_ * I_ / 4);

  // gemm1: grid 16 m-tiles x 148 n-tiles (128 h-cols each) = 2368 (%8==0)
  gemm8p<H_, 296, 0><<<2368, 512, 0, stream>>>(xb, wgub, sgu, (void*)hb);
  // gemm2: grid 16 x 14 = 224 (%8==0)
  gemm8p<I_, 28, 1><<<224, 512, 0, stream>>>(hb, wdb, sd, (void*)out);
}

// Round 9
// 2381.563 us; speedup vs baseline: 1.2989x; 1.0692x over previous
//
#include <hip/hip_runtime.h>

// Qwen2 FP8 MLP on MI355X — 256x256 8-phase MFMA GEMMs (T1+T2+T3+T4+T5).
// fp8-valued fp32 weights cast LOSSLESSLY to bf16; scales in fp32 epilogues.
// gemm1 fuses gate/up + SiLU*mul in-wave via interleaved B-row mapping.
// R6 fix: do_stage clamps (jj>=NT4 -> 0) keeping the vmcnt(2) ledger uniform.
// R7 fix: swizzle upgraded st_16x32 -> full (row&7)<<3 elem XOR. The old
// row-bit2-only XOR left each ds_read_b128 on half the banks (2x floor,
// 1.0e8 conflicts/dispatch). New: bank-quad = (4kk+ksel)^(lrow&7) -> all 32
// banks, 8 accesses/bank = conflict-free floor.

constexpr int T_ = 4096;    // tokens
constexpr int H_ = 3584;    // hidden
constexpr int I_ = 18944;   // intermediate

typedef short s8v __attribute__((ext_vector_type(8)));   // 8 bf16 (4 VGPR)
typedef float f4v __attribute__((ext_vector_type(4)));   // MFMA acc

#define GLOAD_LDS16(g, l) __builtin_amdgcn_global_load_lds( \
    (const __attribute__((address_space(1))) void*)(g),     \
    (__attribute__((address_space(3))) void*)(l), 16, 0, 0)

__device__ __forceinline__ unsigned short f2bf(float f) {
  unsigned int b = __float_as_uint(f);
  return (unsigned short)((b + 0x7FFFu + ((b >> 16) & 1)) >> 16);
}

// ---------------- prepass: fp32 -> bf16 cast ----------------
__global__ void cast_f32_bf16_k(const float* __restrict__ in,
                                unsigned short* __restrict__ out, int n4) {
  int stride = gridDim.x * blockDim.x;
  for (int i = blockIdx.x * blockDim.x + threadIdx.x; i < n4; i += stride) {
    float4 v = reinterpret_cast<const float4*>(in)[i];
    ushort4 o;
    o.x = f2bf(v.x); o.y = f2bf(v.y); o.z = f2bf(v.z); o.w = f2bf(v.w);
    reinterpret_cast<ushort4*>(out)[i] = o;
  }
}

// ---------------- 256x256 8-phase GEMM ----------------
// MODE 0: gemm1. B rows interleave gate/up in 32-row groups; epilogue does
//         silu(g*sg)*(u*su) -> bf16 Hb[T_,I_]. n0 covers 128 h-cols.
// MODE 1: gemm2. Plain B^T; epilogue scales by sd[col] -> fp32 Out[T_,H_].
// Geometry: BM=BN=256, BK=64, 8 waves (2Mx4N), wave tile 128x64,
// frags 8mi x 4ni x 2kk of 16x16x32 bf16. LDS 128KB (2 dbuf x (A,B) x 32KB).
// Swizzle: elem col ^= (row&7)<<3 — linear LDS dest, inverse-swizzled
// GLOBAL source (rule 21), same XOR on ds_read side.
template <int KDIM, int CPX, int MODE>
__global__ __launch_bounds__(512, 2) void gemm8p(
    const unsigned short* __restrict__ A,   // [T_,KDIM] bf16
    const unsigned short* __restrict__ B,   // weights bf16 [*,KDIM]
    const float* __restrict__ S,            // per-out-channel scales
    void* __restrict__ Cout)
{
  constexpr int NT = KDIM / 64;             // K-tiles (56 / 296 — both even)
  constexpr int NT4 = 4 * NT;               // half-tile stages total
  __shared__ unsigned short lds[2][2][2][8192]; // [buf][A/B][half][128*64]

  const int tid = threadIdx.x;
  const int wave = tid >> 6, lane = tid & 63;
  const int wm = wave >> 2, wn = wave & 3;
  const int lrow = lane & 15, ksel = lane >> 4;
  const int sw = (lrow & 7) << 3;           // read-side XOR (elements)
  const int wvb = (wave << 10);             // wave's 1KB slice (bytes)

  const int bid = blockIdx.x;
  const int sid = (bid & 7) * CPX + (bid >> 3);   // XCD-bijective swizzle
  const int m0 = (sid & 15) * 256;
  const int n0 = (sid >> 4) * (MODE == 0 ? 128 : 256);

  f4v acc[8][4];
#pragma unroll
  for (int i = 0; i < 8; ++i)
#pragma unroll
    for (int jv = 0; jv < 4; ++jv)
#pragma unroll
      for (int r = 0; r < 4; ++r) acc[i][jv][r] = 0.f;

  s8v af[4][2], bfr[4][2];

  // stage one half-tile: j -> (ktile, quarter). q: 0=A-h0 1=A-h1 2=B-h0 3=B-h1
  // jj>=NT4: CLAMP to 0 (harmless re-stage of ktile0 A-h0 into dead buf0) so
  // every do_stage issues exactly 2 loads -> vmcnt(2) ledger stays uniform.
  auto do_stage = [&](int jj) {
    if (jj >= NT4) jj = 0;
    const int kt = jj >> 2, q = jj & 3;
    const int buf = kt & 1, k0 = kt << 6;
    const int isB = q >> 1, h = q & 1;
#pragma unroll
    for (int r = 0; r < 2; ++r) {
      int o = r * 8192 + tid * 16;          // byte offset within half (linear)
      int row = o >> 7;
      int cb = (o & 127) ^ ((row & 7) << 4);  // inverse-swizzled source col
      int grow;
      const unsigned short* G;
      if (!isB) { G = A; grow = m0 + h * 128 + row; }
      else {
        G = B;
        if (MODE == 0) {                    // gate/up interleave, 32-row groups
          int rg = h * 128 + row;
          int p = ((rg >> 6) << 5) | (rg & 31);
          grow = n0 + p + (((rg >> 5) & 1) ? I_ : 0);
        } else {
          grow = n0 + h * 128 + row;
        }
      }
      GLOAD_LDS16((const char*)(G + (size_t)grow * KDIM + k0) + cb,
                  (char*)&lds[buf][isB][h][0] + r * 8192 + wvb);
    }
  };

#define LOADA(BUF, MH)                                                        \
  _Pragma("unroll") for (int m = 0; m < 4; ++m)                               \
  _Pragma("unroll") for (int kk = 0; kk < 2; ++kk)                            \
    af[m][kk] = *(const s8v*)&lds[BUF][0][wm]                                 \
        [((MH) * 64 + m * 16 + lrow) * 64 + ((kk * 32 + ksel * 8) ^ sw)];

#define LOADB(BUF, NH)                                                        \
  _Pragma("unroll") for (int n = 0; n < 2; ++n)                               \
  _Pragma("unroll") for (int kk = 0; kk < 2; ++kk)                            \
    bfr[(NH) * 2 + n][kk] = *(const s8v*)&lds[BUF][1][wn >> 1]                \
        [((wn & 1) * 64 + (NH) * 32 + n * 16 + lrow) * 64 +                   \
         ((kk * 32 + ksel * 8) ^ sw)];

#define MFMAQ(MH, NH)                                                         \
  _Pragma("unroll") for (int m = 0; m < 4; ++m)                               \
  _Pragma("unroll") for (int n = 0; n < 2; ++n)                               \
  _Pragma("unroll") for (int kk = 0; kk < 2; ++kk)                            \
    acc[(MH) * 4 + m][(NH) * 2 + n] = __builtin_amdgcn_mfma_f32_16x16x32_bf16(\
        af[m][kk], bfr[(NH) * 2 + n][kk], acc[(MH) * 4 + m][(NH) * 2 + n],    \
        0, 0, 0);

  // ---- prologue: ktile0 (4 halves) + ktile1 A0; drain ktile0 ----
  for (int jj = 0; jj < 5; ++jj) do_stage(jj);
  asm volatile("s_waitcnt vmcnt(2)" ::: "memory");
  __builtin_amdgcn_s_barrier();

  int j = 5;
  for (int kt = 0; kt < NT; ++kt) {
    const int buf = kt & 1;
    // phase 0: quadrant (mh0, nh0)
    LOADA(buf, 0); LOADB(buf, 0);
    do_stage(j++);
    __builtin_amdgcn_s_barrier();
    asm volatile("s_waitcnt lgkmcnt(0)" ::: "memory");
    __builtin_amdgcn_s_setprio(1); MFMAQ(0, 0); __builtin_amdgcn_s_setprio(0);
    __builtin_amdgcn_s_barrier();
    // phase 1: (mh0, nh1)
    LOADB(buf, 1);
    do_stage(j++);
    __builtin_amdgcn_s_barrier();
    asm volatile("s_waitcnt lgkmcnt(0)" ::: "memory");
    __builtin_amdgcn_s_setprio(1); MFMAQ(0, 1); __builtin_amdgcn_s_setprio(0);
    __builtin_amdgcn_s_barrier();
    // phase 2: (mh1, nh1)
    LOADA(buf, 1);
    do_stage(j++);
    __builtin_amdgcn_s_barrier();
    asm volatile("s_waitcnt lgkmcnt(0)" ::: "memory");
    __builtin_amdgcn_s_setprio(1); MFMAQ(1, 1); __builtin_amdgcn_s_setprio(0);
    __builtin_amdgcn_s_barrier();
    // phase 3: (mh1, nh0) — register-resident; counted vmcnt checkpoint
    do_stage(j++);
    __builtin_amdgcn_s_barrier();
    __builtin_amdgcn_s_setprio(1); MFMAQ(1, 0); __builtin_amdgcn_s_setprio(0);
    asm volatile("s_waitcnt vmcnt(2)" ::: "memory");
    __builtin_amdgcn_s_barrier();
  }

  // ---- epilogue ----
  if (MODE == 0) {
    unsigned short* Hb = (unsigned short*)Cout;
#pragma unroll
    for (int np = 0; np < 2; ++np) {
      int colh = n0 + wn * 32 + np * 16 + lrow;
      float sg = S[colh], su = S[I_ + colh];
#pragma unroll
      for (int mi = 0; mi < 8; ++mi) {
        int r0 = m0 + wm * 128 + mi * 16 + ksel * 4;
#pragma unroll
        for (int rg = 0; rg < 4; ++rg) {
          float g = acc[mi][np][rg] * sg;
          float u = acc[mi][np + 2][rg] * su;
          float h = g / (1.f + __expf(-g)) * u;
          Hb[(size_t)(r0 + rg) * I_ + colh] = f2bf(h);
        }
      }
    }
  } else {
    float* O = (float*)Cout;
#pragma unroll
    for (int ni = 0; ni < 4; ++ni) {
      int col = n0 + wn * 64 + ni * 16 + lrow;
      float s = S[col];
#pragma unroll
      for (int mi = 0; mi < 8; ++mi) {
        int r0 = m0 + wm * 128 + mi * 16 + ksel * 4;
#pragma unroll
        for (int rg = 0; rg < 4; ++rg)
          O[(size_t)(r0 + rg) * H_ + col] = acc[mi][ni][rg] * s;
      }
    }
  }
#undef LOADA
#undef LOADB
#undef MFMAQ
}

extern "C" void kernel_launch(void* const* d_in, const int* in_sizes, int n_in,
                              void* d_out, int out_size, void* d_ws, size_t ws_size,
                              hipStream_t stream) {
  const float* x   = (const float*)d_in[0];   // [4096,3584]
  const float* wgu = (const float*)d_in[1];   // [37888,3584]
  const float* sgu = (const float*)d_in[2];   // [37888]
  const float* wd  = (const float*)d_in[3];   // [3584,18944]
  const float* sd  = (const float*)d_in[4];   // [3584]
  float* out = (float*)d_out;                 // [4096,3584] fp32

  // ws: xb | wgu_b | wd_b | hb  (~592 MB, same as validated baseline)
  unsigned short* xb   = (unsigned short*)d_ws;
  unsigned short* wgub = xb + (size_t)T_ * H_;
  unsigned short* wdb  = wgub + (size_t)2 * I_ * H_;
  unsigned short* hb   = wdb + (size_t)H_ * I_;

  cast_f32_bf16_k<<<2048, 256, 0, stream>>>(x, xb, T_ * H_ / 4);
  cast_f32_bf16_k<<<2048, 256, 0, stream>>>(wgu, wgub, 2 * I_ * H_ / 4);
  cast_f32_bf16_k<<<2048, 256, 0, stream>>>(wd, wdb, H_ * I_ / 4);

  // gemm1: grid 16 m-tiles x 148 n-tiles (128 h-cols each) = 2368 (%8==0)
  gemm8p<H_, 296, 0><<<2368, 512, 0, stream>>>(xb, wgub, sgu, (void*)hb);
  // gemm2: grid 16 x 14 = 224 (%8==0)
  gemm8p<I_, 28, 1><<<224, 512, 0, stream>>>(hb, wdb, sd, (void*)out);
}